// Round 5
// baseline (350.133 us; speedup 1.0000x reference)
//
#include <hip/hip_runtime.h>

// B=4, S=2048, D=1024, H=16, Dk=64.  M = B*S = 8192.
// cvt_w(fp32->bf16, weights only) -> proj GEMMs (m97 2-barrier structure;
// A = fp32 Q/K/V staged ASYNC via GLD16 into fp32 LDS + in-reg cvt;
// B = bf16 weights, r4-verified swizzled path; q/k [bh][s][dk], v^T
// sigma-permuted [bh][dk][s], q pre-scaled 0.125*log2e) -> flash attn v3
// (double-buffered K/Vt, issue-early/drain-late) -> out GEMM (r4 core).
//
// LDS swizzle (verified r3/r4, 0 bank conflicts): rows of 128B, 8 slots of
// 16B, slot = chunk ^ (row&7).  GLD16 keeps a LINEAR LDS dest (HW rule);
// the permutation is baked into the per-lane GLOBAL source address; ds_read
// applies the same XOR.  fp32 A tile: [128 rows][32 k] fp32 = 128B rows,
// chunk = 4 floats; fragment = 2 x f32x4 reads + 8 cvts.

typedef __bf16 bhalf_t;
typedef __attribute__((ext_vector_type(8)))  __bf16 bf16x8;
typedef __attribute__((ext_vector_type(4)))  __bf16 bf16x4;
typedef __attribute__((ext_vector_type(4)))  float  f32x4;
typedef __attribute__((ext_vector_type(16))) float  f32x16;

typedef __attribute__((address_space(1))) void gvoid_t;
typedef __attribute__((address_space(3))) void lvoid_t;
#define GLD16(g, l) __builtin_amdgcn_global_load_lds((const gvoid_t*)(g), (lvoid_t*)(l), 16, 0, 0)

// ---------------------------------------------------------------------------
// Weights-only fp32 -> bf16 (4 x [1024x1024]); Q/K/V convert inside proj.
// ---------------------------------------------------------------------------
__global__ __launch_bounds__(256) void cvt_w(
    const float* __restrict__ Wq, const float* __restrict__ Wk,
    const float* __restrict__ Wv, const float* __restrict__ Wo,
    bhalf_t* __restrict__ Wqb, bhalf_t* __restrict__ Wkb,
    bhalf_t* __restrict__ Wvb, bhalf_t* __restrict__ Wob)
{
  size_t t = (size_t)blockIdx.x * 256 + threadIdx.x;   // float4 index
  int w = (int)(t >> 18); t &= 262143;
  const float* src = (w == 0) ? Wq  : (w == 1) ? Wk  : (w == 2) ? Wv  : Wo;
  bhalf_t*     dst = (w == 0) ? Wqb : (w == 1) ? Wkb : (w == 2) ? Wvb : Wob;
  float4 f = ((const float4*)src)[t];
  bf16x4 o;
  o.x = (bhalf_t)f.x; o.y = (bhalf_t)f.y; o.z = (bhalf_t)f.z; o.w = (bhalf_t)f.w;
  ((bf16x4*)dst)[t] = o;
}

// ---------------------------------------------------------------------------
// Swizzled m97 core, bf16 A and B (r4-verified, 0 conflicts).  out_gemm.
// ---------------------------------------------------------------------------
__device__ __forceinline__ void gemm_core_128_swz(
    const bhalf_t* __restrict__ A, const bhalf_t* __restrict__ B,
    int bm, int bn, bhalf_t* As, bhalf_t* Bs, f32x4 acc[4][4])
{
  const int tid = threadIdx.x, lane = tid & 63, wave = tid >> 6;
  const int wm = wave >> 1, wn = wave & 1;
  const int quad = lane >> 4, tn = lane & 15;

  const int u    = (lane & 7) ^ (lane >> 3);
  const int roff = (lane >> 3) + 64 * (u >> 2);
  const int gk   = (u & 3) * 8;

  const bhalf_t* Ag0 = A + (size_t)(bm * 128 + wave * 8 + roff) * 1024 + gk;
  const bhalf_t* Ag1 = A + (size_t)(bm * 128 + (wave + 4) * 8 + roff) * 1024 + gk;
  const bhalf_t* Bg0 = B + (size_t)(bn * 128 + wave * 8 + roff) * 1024 + gk;
  const bhalf_t* Bg1 = B + (size_t)(bn * 128 + (wave + 4) * 8 + roff) * 1024 + gk;
  bhalf_t* Ad0 = As + wave * 512;  bhalf_t* Ad1 = As + (wave + 4) * 512;
  bhalf_t* Bd0 = Bs + wave * 512;  bhalf_t* Bd1 = Bs + (wave + 4) * 512;

  const int aswz = ((wm * 4 + quad) ^ (tn & 7)) * 8;
  const int bswz = ((wn * 4 + quad) ^ (tn & 7)) * 8;

  for (int k0 = 0; k0 < 1024; k0 += 32) {
    GLD16(Ag0 + k0, Ad0);
    GLD16(Ag1 + k0, Ad1);
    GLD16(Bg0 + k0, Bd0);
    GLD16(Bg1 + k0, Bd1);
    __syncthreads();
    bf16x8 af[4], bfr[4];
#pragma unroll
    for (int i = 0; i < 4; ++i)
      af[i] = *(const bf16x8*)(As + (i * 16 + tn) * 64 + aswz);
#pragma unroll
    for (int j = 0; j < 4; ++j)
      bfr[j] = *(const bf16x8*)(Bs + (j * 16 + tn) * 64 + bswz);
#pragma unroll
    for (int i = 0; i < 4; ++i)
#pragma unroll
      for (int j = 0; j < 4; ++j)
        acc[i][j] = __builtin_amdgcn_mfma_f32_16x16x32_bf16(af[i], bfr[j], acc[i][j], 0, 0, 0);
    __syncthreads();
  }
}

// ---------------------------------------------------------------------------
// Fused q/k/v projection.  A = fp32 Q/K/V staged ASYNC via GLD16 into a
// [128][32] fp32 LDS tile (slot = chunk4 ^ (row&7)); fragments read as
// 2 x f32x4 + 8 in-reg cvts.  B = bf16 weights, verified swizzled path.
// q scaled by 0.125*log2e; v stored transposed [bh][dk][s], s sigma-perm.
// Block mapping: bm = idx&63 (fast) so XCD = bm%8 -> per-XCD A-slab reuse.
// ---------------------------------------------------------------------------
__global__ __launch_bounds__(256) void proj_gemm(
    const float* __restrict__ Qf, const float* __restrict__ Kf, const float* __restrict__ Vf,
    const bhalf_t* __restrict__ Wqb, const bhalf_t* __restrict__ Wkb, const bhalf_t* __restrict__ Wvb,
    const float* __restrict__ bq, const float* __restrict__ bk, const float* __restrict__ bv,
    bhalf_t* __restrict__ qo, bhalf_t* __restrict__ ko, bhalf_t* __restrict__ vto)
{
  __shared__ float   Asf[4096];   // [128][32] fp32, 16 KB, swizzled slots
  __shared__ bhalf_t Bs[4096];    // [64][128B] bf16, 8 KB (r4-verified)
  const int seg = blockIdx.x >> 9;
  const int idx = blockIdx.x & 511;
  const int bm = idx & 63, bn = idx >> 6;    // XCD-aware: bm fast-varying

  const float *A; const bhalf_t *Bw; const float* bias; bhalf_t* out; float scale; int mode;
  if (seg == 0)      { A = Qf; Bw = Wqb; bias = bq; out = qo;  scale = 0.18033688f; mode = 0; }
  else if (seg == 1) { A = Kf; Bw = Wkb; bias = bk; out = ko;  scale = 1.0f;        mode = 0; }
  else               { A = Vf; Bw = Wvb; bias = bv; out = vto; scale = 1.0f;        mode = 1; }

  const int tid = threadIdx.x, lane = tid & 63, wave = tid >> 6;
  const int wm = wave >> 1, wn = wave & 1;
  const int quad = lane >> 4, tn = lane & 15;

  const int u = (lane & 7) ^ (lane >> 3);   // swizzled chunk held by this lane

  // A staging (fp32): wave stages 4 x 1KB chunk-groups C = wave*4+i
  // (8 rows each); lane covers row C*8+(lane>>3), 4-float chunk u.
  const float* Ag[4];
#pragma unroll
  for (int i = 0; i < 4; ++i)
    Ag[i] = A + (size_t)(bm * 128 + wave * 32 + i * 8 + (lane >> 3)) * 1024 + u * 4;

  // B staging (bf16, verified): row-paired layout, chunks wave and wave+4.
  const int roffB = (lane >> 3) + 64 * (u >> 2);
  const int gkB   = (u & 3) * 8;
  const bhalf_t* Bg0 = Bw + (size_t)(bn * 128 + wave * 8 + roffB) * 1024 + gkB;
  const bhalf_t* Bg1 = Bw + (size_t)(bn * 128 + (wave + 4) * 8 + roffB) * 1024 + gkB;
  bhalf_t* Bd0 = Bs + wave * 512;
  bhalf_t* Bd1 = Bs + (wave + 4) * 512;

  // fragment read geometry
  const int arow = (wm * 64 + tn) * 32;             // + i*16*32 floats
  const int alo  = ((2 * quad)     ^ (tn & 7)) * 4; // lo 4-float chunk slot
  const int ahi  = ((2 * quad + 1) ^ (tn & 7)) * 4; // hi 4-float chunk slot
  const int bswz = ((wn * 4 + quad) ^ (tn & 7)) * 8;

  f32x4 acc[4][4];
#pragma unroll
  for (int i = 0; i < 4; ++i)
#pragma unroll
    for (int j = 0; j < 4; ++j)
      acc[i][j] = (f32x4){0.f, 0.f, 0.f, 0.f};

  for (int k0 = 0; k0 < 1024; k0 += 32) {
    GLD16(Bg0 + k0, Bd0);
    GLD16(Bg1 + k0, Bd1);
#pragma unroll
    for (int i = 0; i < 4; ++i)
      GLD16(Ag[i] + k0, Asf + (wave * 4 + i) * 256);
    __syncthreads();
    bf16x8 af[4], bfr[4];
#pragma unroll
    for (int i = 0; i < 4; ++i) {
      const f32x4 lo = *(const f32x4*)(Asf + arow + i * 512 + alo);
      const f32x4 hi = *(const f32x4*)(Asf + arow + i * 512 + ahi);
      bf16x8 v;
      v[0] = (bhalf_t)lo[0]; v[1] = (bhalf_t)lo[1];
      v[2] = (bhalf_t)lo[2]; v[3] = (bhalf_t)lo[3];
      v[4] = (bhalf_t)hi[0]; v[5] = (bhalf_t)hi[1];
      v[6] = (bhalf_t)hi[2]; v[7] = (bhalf_t)hi[3];
      af[i] = v;
    }
#pragma unroll
    for (int j = 0; j < 4; ++j)
      bfr[j] = *(const bf16x8*)(Bs + (j * 16 + tn) * 64 + bswz);
#pragma unroll
    for (int i = 0; i < 4; ++i)
#pragma unroll
      for (int j = 0; j < 4; ++j)
        acc[i][j] = __builtin_amdgcn_mfma_f32_16x16x32_bf16(af[i], bfr[j], acc[i][j], 0, 0, 0);
    __syncthreads();
  }

  // epilogue: bias + scale, mode-dependent scatter (verified r0/r4)
#pragma unroll
  for (int i = 0; i < 4; ++i)
#pragma unroll
    for (int j = 0; j < 4; ++j) {
      const int n = bn * 128 + wn * 64 + j * 16 + tn;
      const float bsv = bias[n];
      const int h = n >> 6, dk = n & 63;
#pragma unroll
      for (int r = 0; r < 4; ++r) {
        const int m = bm * 128 + wm * 64 + i * 16 + quad * 4 + r;
        const int b = m >> 11, s = m & 2047;
        const float v = (acc[i][j][r] + bsv) * scale;
        size_t addr;
        if (mode == 0) addr = (((size_t)(b * 16 + h)) * 2048 + s) * 64 + dk;
        else {
          const int s2 = (s & ~12) | ((s & 4) << 1) | ((s & 8) >> 1);  // sigma
          addr = (((size_t)(b * 16 + h)) * 64 + dk) * 2048 + s2;
        }
        out[addr] = (bhalf_t)v;
      }
    }
}

// ---------------------------------------------------------------------------
__global__ __launch_bounds__(256) void out_gemm(
    const bhalf_t* __restrict__ A, const bhalf_t* __restrict__ Bw,
    const float* __restrict__ bias, float* __restrict__ Cout)
{
  __shared__ bhalf_t As[4096];
  __shared__ bhalf_t Bs[4096];
  const int bm = blockIdx.x & 63, bn = blockIdx.x >> 6;   // XCD-aware

  f32x4 acc[4][4];
#pragma unroll
  for (int i = 0; i < 4; ++i)
#pragma unroll
    for (int j = 0; j < 4; ++j)
      acc[i][j] = (f32x4){0.f, 0.f, 0.f, 0.f};

  gemm_core_128_swz(A, Bw, bm, bn, As, Bs, acc);

  const int lane = threadIdx.x & 63, wave = threadIdx.x >> 6;
  const int wm = wave >> 1, wn = wave & 1, quad = lane >> 4, tn = lane & 15;
#pragma unroll
  for (int i = 0; i < 4; ++i)
#pragma unroll
    for (int j = 0; j < 4; ++j) {
      const int n = bn * 128 + wn * 64 + j * 16 + tn;
      const float bsv = bias[n];
#pragma unroll
      for (int r = 0; r < 4; ++r) {
        const int m = bm * 128 + wm * 64 + i * 16 + quad * 4 + r;
        Cout[(size_t)m * 1024 + n] = acc[i][j][r] + bsv;
      }
    }
}

// ---------------------------------------------------------------------------
// Flash attention v3 + double-buffered K/Vt (issue-early / drain-late).
// Block = 4 waves x 64 q rows; kv tiles of 64.  Per iter: issue GLD16 for
// tile t+1 into buf^1, compute tile t from buf, ONE __syncthreads() (its
// vmcnt(0) drain lands after ~750 cyc of MFMA+exp2 has hidden the HBM
// latency).  buf[nxt] was last read before the previous barrier -> safe.
// ---------------------------------------------------------------------------
__global__ __launch_bounds__(256, 2) void attn_kernel(
    const bhalf_t* __restrict__ qp, const bhalf_t* __restrict__ kp,
    const bhalf_t* __restrict__ vtp, bhalf_t* __restrict__ outp)
{
  __shared__ bhalf_t Klds[2][4096];    // [64 kv][64 dk], XOR-swizzled chunks
  __shared__ bhalf_t Vtlds[2][4096];   // [64 dk][64 kv(sigma)], XOR-swizzled

  const int tid = threadIdx.x, lane = tid & 63, wave = tid >> 6;
  const int q31 = lane & 31, h = lane >> 5;
  const int bh = blockIdx.y, qt = blockIdx.x;

  const bhalf_t* qbase = qp + (((size_t)bh * 2048) + qt * 256 + wave * 64 + q31) * 64;
  bf16x8 qf[2][4];
#pragma unroll
  for (int qs = 0; qs < 2; ++qs)
#pragma unroll
    for (int ks = 0; ks < 4; ++ks)
      qf[qs][ks] = *(const bf16x8*)(qbase + qs * 32 * 64 + ks * 16 + h * 8);

  f32x16 Ot[2][2];
#pragma unroll
  for (int qs = 0; qs < 2; ++qs)
#pragma unroll
    for (int dd = 0; dd < 2; ++dd)
#pragma unroll
      for (int i = 0; i < 16; ++i) Ot[qs][dd][i] = 0.f;
  float Lp[2] = {0.f, 0.f};

  const bhalf_t* kbase  = kp  + (size_t)bh * 2048 * 64;
  const bhalf_t* vtbase = vtp + (size_t)bh * 64 * 2048;

  const int rloc = lane >> 3;                 // staging row within 8-row chunk
  const int cg8  = ((lane & 7) ^ rloc) * 8;   // swizzled source chunk (elems)
  const int q7 = q31 & 7;

  // prologue: stage tile 0 into buffer 0
#pragma unroll
  for (int i = 0; i < 2; ++i) {
    const int r0 = (wave * 2 + i) * 8;
    GLD16(kbase + (size_t)(r0 + rloc) * 64 + cg8, &Klds[0][r0 * 64]);
    GLD16(vtbase + (size_t)(r0 + rloc) * 2048 + cg8, &Vtlds[0][r0 * 64]);
  }
  __syncthreads();

  for (int kv0 = 0; kv0 < 2048; kv0 += 64) {
    const int cur = (kv0 >> 6) & 1, nxt = cur ^ 1;
    if (kv0 < 2048 - 64) {   // issue next tile early (latency hides under compute)
#pragma unroll
      for (int i = 0; i < 2; ++i) {
        const int r0 = (wave * 2 + i) * 8;
        GLD16(kbase + (size_t)(kv0 + 64 + r0 + rloc) * 64 + cg8, &Klds[nxt][r0 * 64]);
        GLD16(vtbase + (size_t)(r0 + rloc) * 2048 + (kv0 + 64) + cg8, &Vtlds[nxt][r0 * 64]);
      }
    }
    const bhalf_t* Kc = Klds[cur];
    const bhalf_t* Vc = Vtlds[cur];

    // S^T + exp2 + pack into PV B-fragments (register-only)
    bf16x8 pb[2][4];
#pragma unroll
    for (int mb = 0; mb < 2; ++mb) {
      bf16x8 ka[4];
#pragma unroll
      for (int ks = 0; ks < 4; ++ks)
        ka[ks] = *(const bf16x8*)(Kc + (mb * 32 + q31) * 64 + ((2 * ks + h) ^ q7) * 8);
#pragma unroll
      for (int qs = 0; qs < 2; ++qs) {
        f32x16 S;
#pragma unroll
        for (int i = 0; i < 16; ++i) S[i] = 0.f;
#pragma unroll
        for (int ks = 0; ks < 4; ++ks)
          S = __builtin_amdgcn_mfma_f32_32x32x16_bf16(ka[ks], qf[qs][ks], S, 0, 0, 0);
        float ls = 0.f;
#pragma unroll
        for (int half = 0; half < 2; ++half) {
          bf16x8 pk;
#pragma unroll
          for (int j = 0; j < 8; ++j) {
            const float e = __builtin_amdgcn_exp2f(S[half * 8 + j]);
            ls += e;
            pk[j] = (bhalf_t)e;
          }
          pb[qs][mb * 2 + half] = pk;
        }
        Lp[qs] += ls;
      }
    }

    // O^T += Vt @ P
#pragma unroll
    for (int dd = 0; dd < 2; ++dd)
#pragma unroll
      for (int kb = 0; kb < 4; ++kb) {
        const bf16x8 va = *(const bf16x8*)(Vc + (dd * 32 + q31) * 64 + ((2 * kb + h) ^ q7) * 8);
#pragma unroll
        for (int qs = 0; qs < 2; ++qs)
          Ot[qs][dd] = __builtin_amdgcn_mfma_f32_32x32x16_bf16(va, pb[qs][kb], Ot[qs][dd], 0, 0, 0);
      }
    __syncthreads();   // drains vmcnt (next tile landed) + read-release of buf
  }

  const int b = bh >> 4, hh = bh & 15;
#pragma unroll
  for (int qs = 0; qs < 2; ++qs) {
    const float Lt = Lp[qs] + __shfl_xor(Lp[qs], 32, 64);
    const float linv = 1.0f / Lt;
    const int s = qt * 256 + wave * 64 + qs * 32 + q31;
    bhalf_t* ob = outp + ((size_t)(b * 2048 + s)) * 1024 + hh * 64;
#pragma unroll
    for (int dd = 0; dd < 2; ++dd)
#pragma unroll
      for (int g = 0; g < 4; ++g) {
        bf16x4 o;
        o.x = (bhalf_t)(Ot[qs][dd][4 * g + 0] * linv);
        o.y = (bhalf_t)(Ot[qs][dd][4 * g + 1] * linv);
        o.z = (bhalf_t)(Ot[qs][dd][4 * g + 2] * linv);
        o.w = (bhalf_t)(Ot[qs][dd][4 * g + 3] * linv);
        *(bf16x4*)(ob + dd * 32 + g * 8 + h * 4) = o;
      }
  }
}

// ---------------------------------------------------------------------------
extern "C" void kernel_launch(void* const* d_in, const int* in_sizes, int n_in,
                              void* d_out, int out_size, void* d_ws, size_t ws_size,
                              hipStream_t stream)
{
  const float* Q  = (const float*)d_in[0];
  const float* K  = (const float*)d_in[1];
  const float* V  = (const float*)d_in[2];
  const float* Wq = (const float*)d_in[3];
  const float* bq = (const float*)d_in[4];
  const float* Wk = (const float*)d_in[5];
  const float* bk = (const float*)d_in[6];
  const float* Wv = (const float*)d_in[7];
  const float* bv = (const float*)d_in[8];
  const float* Wo = (const float*)d_in[9];
  const float* bo = (const float*)d_in[10];

  char* ws = (char*)d_ws;
  const size_t SZ = 8192ull * 1024 * 2;   // 16 MB  [8192,1024] bf16
  const size_t WZ = 1024ull * 1024 * 2;   //  2 MB  [1024,1024] bf16
  bhalf_t* Wqb  = (bhalf_t*)(ws);
  bhalf_t* Wkb  = (bhalf_t*)(ws + WZ);
  bhalf_t* Wvb  = (bhalf_t*)(ws + 2 * WZ);
  bhalf_t* Wob  = (bhalf_t*)(ws + 3 * WZ);
  bhalf_t* q_p  = (bhalf_t*)(ws + 4 * WZ);
  bhalf_t* k_p  = (bhalf_t*)(ws + 4 * WZ + SZ);
  bhalf_t* vt_p = (bhalf_t*)(ws + 4 * WZ + 2 * SZ);
  bhalf_t* attn_o = (bhalf_t*)(ws + 4 * WZ + 3 * SZ);

  cvt_w<<<4096, 256, 0, stream>>>(Wq, Wk, Wv, Wo, Wqb, Wkb, Wvb, Wob);
  proj_gemm<<<1536, 256, 0, stream>>>(Q, K, V, Wqb, Wkb, Wvb,
                                      bq, bk, bv, q_p, k_p, vt_p);
  attn_kernel<<<dim3(8, 64), 256, 0, stream>>>(q_p, k_p, vt_p, attn_o);
  out_gemm<<<512, 256, 0, stream>>>(attn_o, Wob, bo, (float*)d_out);
}

// Round 6
// 330.427 us; speedup vs baseline: 1.0596x; 1.0596x over previous
//
#include <hip/hip_runtime.h>

// B=4, S=2048, D=1024, H=16, Dk=64.  M = B*S = 8192.
// cvt(fp32->bf16) -> proj GEMMs (128^2 tile, BK=64 2-barrier loop, swizzled
// LDS; q/k [bh][s][dk], v^T sigma-permuted [bh][dk][s], q pre-scaled
// 0.125*log2e) -> flash attn v3 (dbuf K/Vt issue-early/drain-late, grid
// (bh,qt) so all 8 qt-blocks of a bh share one XCD's L2) -> out GEMM
// (r4-verified BK=32 core, unchanged anchor).  Workspace: 104 MB.
//
// LDS swizzle (r4-verified 0-conflict involution): 128B rows, 8 slots of
// 16B, slot = chunk ^ (row&7).  GLD16 keeps a LINEAR LDS dest (HW rule);
// the permutation is baked into the per-lane GLOBAL source address
// (src_chunk = (lane&7)^(lane>>3)); ds_read applies the same XOR.
// BK=64 proj tile [128][64] bf16 has natural 128B rows -> no row-pairing.

typedef __bf16 bhalf_t;
typedef __attribute__((ext_vector_type(8)))  __bf16 bf16x8;
typedef __attribute__((ext_vector_type(4)))  __bf16 bf16x4;
typedef __attribute__((ext_vector_type(4)))  float  f32x4;
typedef __attribute__((ext_vector_type(16))) float  f32x16;

typedef __attribute__((address_space(1))) void gvoid_t;
typedef __attribute__((address_space(3))) void lvoid_t;
#define GLD16(g, l) __builtin_amdgcn_global_load_lds((const gvoid_t*)(g), (lvoid_t*)(l), 16, 0, 0)

// ---------------------------------------------------------------------------
__global__ __launch_bounds__(256) void cvt_all(
    const float* __restrict__ Q, const float* __restrict__ Kin, const float* __restrict__ V,
    const float* __restrict__ Wq, const float* __restrict__ Wk, const float* __restrict__ Wv,
    const float* __restrict__ Wo,
    bhalf_t* __restrict__ Qb, bhalf_t* __restrict__ Kb, bhalf_t* __restrict__ Vb,
    bhalf_t* __restrict__ Wqb, bhalf_t* __restrict__ Wkb, bhalf_t* __restrict__ Wvb,
    bhalf_t* __restrict__ Wob)
{
  size_t t = (size_t)blockIdx.x * 256 + threadIdx.x;   // float4 index
  const float* src; bhalf_t* dst;
  if (t < 2097152)      { src = Q;   dst = Qb; }
  else if (t < 4194304) { src = Kin; dst = Kb; t -= 2097152; }
  else if (t < 6291456) { src = V;   dst = Vb; t -= 4194304; }
  else {
    t -= 6291456;
    int w = (int)(t >> 18); t &= 262143;
    src = (w == 0) ? Wq  : (w == 1) ? Wk  : (w == 2) ? Wv  : Wo;
    dst = (w == 0) ? Wqb : (w == 1) ? Wkb : (w == 2) ? Wvb : Wob;
  }
  float4 f = ((const float4*)src)[t];
  bf16x4 o;
  o.x = (bhalf_t)f.x; o.y = (bhalf_t)f.y; o.z = (bhalf_t)f.z; o.w = (bhalf_t)f.w;
  ((bf16x4*)dst)[t] = o;
}

// ---------------------------------------------------------------------------
// r4-verified swizzled BK=32 core (unchanged anchor): used by out_gemm.
// ---------------------------------------------------------------------------
__device__ __forceinline__ void gemm_core_128_swz(
    const bhalf_t* __restrict__ A, const bhalf_t* __restrict__ B,
    int bm, int bn, bhalf_t* As, bhalf_t* Bs, f32x4 acc[4][4])
{
  const int tid = threadIdx.x, lane = tid & 63, wave = tid >> 6;
  const int wm = wave >> 1, wn = wave & 1;
  const int quad = lane >> 4, tn = lane & 15;

  const int u    = (lane & 7) ^ (lane >> 3);
  const int roff = (lane >> 3) + 64 * (u >> 2);
  const int gk   = (u & 3) * 8;

  const bhalf_t* Ag0 = A + (size_t)(bm * 128 + wave * 8 + roff) * 1024 + gk;
  const bhalf_t* Ag1 = A + (size_t)(bm * 128 + (wave + 4) * 8 + roff) * 1024 + gk;
  const bhalf_t* Bg0 = B + (size_t)(bn * 128 + wave * 8 + roff) * 1024 + gk;
  const bhalf_t* Bg1 = B + (size_t)(bn * 128 + (wave + 4) * 8 + roff) * 1024 + gk;
  bhalf_t* Ad0 = As + wave * 512;  bhalf_t* Ad1 = As + (wave + 4) * 512;
  bhalf_t* Bd0 = Bs + wave * 512;  bhalf_t* Bd1 = Bs + (wave + 4) * 512;

  const int aswz = ((wm * 4 + quad) ^ (tn & 7)) * 8;
  const int bswz = ((wn * 4 + quad) ^ (tn & 7)) * 8;

  for (int k0 = 0; k0 < 1024; k0 += 32) {
    GLD16(Ag0 + k0, Ad0);
    GLD16(Ag1 + k0, Ad1);
    GLD16(Bg0 + k0, Bd0);
    GLD16(Bg1 + k0, Bd1);
    __syncthreads();
    bf16x8 af[4], bfr[4];
#pragma unroll
    for (int i = 0; i < 4; ++i)
      af[i] = *(const bf16x8*)(As + (i * 16 + tn) * 64 + aswz);
#pragma unroll
    for (int j = 0; j < 4; ++j)
      bfr[j] = *(const bf16x8*)(Bs + (j * 16 + tn) * 64 + bswz);
#pragma unroll
    for (int i = 0; i < 4; ++i)
#pragma unroll
      for (int j = 0; j < 4; ++j)
        acc[i][j] = __builtin_amdgcn_mfma_f32_16x16x32_bf16(af[i], bfr[j], acc[i][j], 0, 0, 0);
    __syncthreads();
  }
}

// ---------------------------------------------------------------------------
// Fused q/k/v projection, BK=64: [128][64] bf16 tiles (16 KB each), 16
// K-iterations (half the barrier drains of BK=32).  Staging: 1024 16B
// chunks/tile, thread stages 4 (d = g*256+tid; row=d>>3, slot=d&7,
// src_chunk = slot^(row&7) = (lane&7)^(lane>>3) since row&7=(lane>>3)&7).
// Fragment read: row = w*64+i*16+tn, slot = (kk*4+quad)^(tn&7).
// q scaled by 0.125*log2e; v stored transposed [bh][dk][s], s sigma-perm.
// Block mapping: bm = idx&63 (fast) so XCD = bm%8 -> per-XCD A-slab reuse.
// ---------------------------------------------------------------------------
__global__ __launch_bounds__(256) void proj_gemm(
    const bhalf_t* __restrict__ Qb, const bhalf_t* __restrict__ Kb, const bhalf_t* __restrict__ Vb,
    const bhalf_t* __restrict__ Wqb, const bhalf_t* __restrict__ Wkb, const bhalf_t* __restrict__ Wvb,
    const float* __restrict__ bq, const float* __restrict__ bk, const float* __restrict__ bv,
    bhalf_t* __restrict__ qo, bhalf_t* __restrict__ ko, bhalf_t* __restrict__ vto)
{
  __shared__ bhalf_t As[8192];   // [128][64] bf16, 16 KB, swizzled slots
  __shared__ bhalf_t Bs[8192];
  const int seg = blockIdx.x >> 9;
  const int idx = blockIdx.x & 511;
  const int bm = idx & 63, bn = idx >> 6;    // XCD-aware: bm fast-varying

  const bhalf_t *A, *Bw; const float* bias; bhalf_t* out; float scale; int mode;
  if (seg == 0)      { A = Qb; Bw = Wqb; bias = bq; out = qo;  scale = 0.18033688f; mode = 0; }
  else if (seg == 1) { A = Kb; Bw = Wkb; bias = bk; out = ko;  scale = 1.0f;        mode = 0; }
  else               { A = Vb; Bw = Wvb; bias = bv; out = vto; scale = 1.0f;        mode = 1; }

  const int tid = threadIdx.x, lane = tid & 63, wave = tid >> 6;
  const int wm = wave >> 1, wn = wave & 1;
  const int quad = lane >> 4, tn = lane & 15;
  const int u = (lane & 7) ^ (lane >> 3);

  const bhalf_t* Agp[4]; const bhalf_t* Bgp[4];
#pragma unroll
  for (int g = 0; g < 4; ++g) {
    const int row = g * 32 + wave * 8 + (lane >> 3);
    Agp[g] = A  + (size_t)(bm * 128 + row) * 1024 + u * 8;
    Bgp[g] = Bw + (size_t)(bn * 128 + row) * 1024 + u * 8;
  }

  f32x4 acc[4][4];
#pragma unroll
  for (int i = 0; i < 4; ++i)
#pragma unroll
    for (int j = 0; j < 4; ++j)
      acc[i][j] = (f32x4){0.f, 0.f, 0.f, 0.f};

  for (int k0 = 0; k0 < 1024; k0 += 64) {
#pragma unroll
    for (int g = 0; g < 4; ++g) {
      GLD16(Agp[g] + k0, As + g * 2048 + wave * 512);
      GLD16(Bgp[g] + k0, Bs + g * 2048 + wave * 512);
    }
    __syncthreads();
#pragma unroll
    for (int kk = 0; kk < 2; ++kk) {
      bf16x8 af[4], bfr[4];
#pragma unroll
      for (int i = 0; i < 4; ++i)
        af[i] = *(const bf16x8*)(As + (wm * 64 + i * 16 + tn) * 64
                                    + (((kk * 4 + quad) ^ (tn & 7)) * 8));
#pragma unroll
      for (int j = 0; j < 4; ++j)
        bfr[j] = *(const bf16x8*)(Bs + (wn * 64 + j * 16 + tn) * 64
                                     + (((kk * 4 + quad) ^ (tn & 7)) * 8));
#pragma unroll
      for (int i = 0; i < 4; ++i)
#pragma unroll
        for (int j = 0; j < 4; ++j)
          acc[i][j] = __builtin_amdgcn_mfma_f32_16x16x32_bf16(af[i], bfr[j], acc[i][j], 0, 0, 0);
    }
    __syncthreads();
  }

  // epilogue: bias + scale, mode-dependent scatter (verified r0/r4)
  const int lane2 = threadIdx.x & 63, wave2 = threadIdx.x >> 6;
  const int wm2 = wave2 >> 1, wn2 = wave2 & 1, quad2 = lane2 >> 4, tn2 = lane2 & 15;
#pragma unroll
  for (int i = 0; i < 4; ++i)
#pragma unroll
    for (int j = 0; j < 4; ++j) {
      const int n = bn * 128 + wn2 * 64 + j * 16 + tn2;
      const float bsv = bias[n];
      const int h = n >> 6, dk = n & 63;
#pragma unroll
      for (int r = 0; r < 4; ++r) {
        const int m = bm * 128 + wm2 * 64 + i * 16 + quad2 * 4 + r;
        const int b = m >> 11, s = m & 2047;
        const float v = (acc[i][j][r] + bsv) * scale;
        size_t addr;
        if (mode == 0) addr = (((size_t)(b * 16 + h)) * 2048 + s) * 64 + dk;
        else {
          const int s2 = (s & ~12) | ((s & 4) << 1) | ((s & 8) >> 1);  // sigma
          addr = (((size_t)(b * 16 + h)) * 64 + dk) * 2048 + s2;
        }
        out[addr] = (bhalf_t)v;
      }
    }
}

// ---------------------------------------------------------------------------
__global__ __launch_bounds__(256) void out_gemm(
    const bhalf_t* __restrict__ A, const bhalf_t* __restrict__ Bw,
    const float* __restrict__ bias, float* __restrict__ Cout)
{
  __shared__ bhalf_t As[4096];
  __shared__ bhalf_t Bs[4096];
  const int bm = blockIdx.x & 63, bn = blockIdx.x >> 6;   // XCD-aware

  f32x4 acc[4][4];
#pragma unroll
  for (int i = 0; i < 4; ++i)
#pragma unroll
    for (int j = 0; j < 4; ++j)
      acc[i][j] = (f32x4){0.f, 0.f, 0.f, 0.f};

  gemm_core_128_swz(A, Bw, bm, bn, As, Bs, acc);

  const int lane = threadIdx.x & 63, wave = threadIdx.x >> 6;
  const int wm = wave >> 1, wn = wave & 1, quad = lane >> 4, tn = lane & 15;
#pragma unroll
  for (int i = 0; i < 4; ++i)
#pragma unroll
    for (int j = 0; j < 4; ++j) {
      const int n = bn * 128 + wn * 64 + j * 16 + tn;
      const float bsv = bias[n];
#pragma unroll
      for (int r = 0; r < 4; ++r) {
        const int m = bm * 128 + wm * 64 + i * 16 + quad * 4 + r;
        Cout[(size_t)m * 1024 + n] = acc[i][j][r] + bsv;
      }
    }
}

// ---------------------------------------------------------------------------
// Flash attention v3, double-buffered K/Vt (r5-verified).  Grid (64,8):
// bh = blockIdx.x, qt = blockIdx.y -> linear id = qt*64+bh -> XCD = bh%8,
// so all 8 qt-blocks sharing one bh's 512KB K/V stream live on ONE XCD
// (L2-served after first touch; old (8,64) grid spread them over all 8).
// ---------------------------------------------------------------------------
__global__ __launch_bounds__(256, 2) void attn_kernel(
    const bhalf_t* __restrict__ qp, const bhalf_t* __restrict__ kp,
    const bhalf_t* __restrict__ vtp, bhalf_t* __restrict__ outp)
{
  __shared__ bhalf_t Klds[2][4096];    // [64 kv][64 dk], XOR-swizzled chunks
  __shared__ bhalf_t Vtlds[2][4096];   // [64 dk][64 kv(sigma)], XOR-swizzled

  const int tid = threadIdx.x, lane = tid & 63, wave = tid >> 6;
  const int q31 = lane & 31, h = lane >> 5;
  const int bh = blockIdx.x, qt = blockIdx.y;   // XCD-local K/V sharing

  const bhalf_t* qbase = qp + (((size_t)bh * 2048) + qt * 256 + wave * 64 + q31) * 64;
  bf16x8 qf[2][4];
#pragma unroll
  for (int qs = 0; qs < 2; ++qs)
#pragma unroll
    for (int ks = 0; ks < 4; ++ks)
      qf[qs][ks] = *(const bf16x8*)(qbase + qs * 32 * 64 + ks * 16 + h * 8);

  f32x16 Ot[2][2];
#pragma unroll
  for (int qs = 0; qs < 2; ++qs)
#pragma unroll
    for (int dd = 0; dd < 2; ++dd)
#pragma unroll
      for (int i = 0; i < 16; ++i) Ot[qs][dd][i] = 0.f;
  float Lp[2] = {0.f, 0.f};

  const bhalf_t* kbase  = kp  + (size_t)bh * 2048 * 64;
  const bhalf_t* vtbase = vtp + (size_t)bh * 64 * 2048;

  const int rloc = lane >> 3;                 // staging row within 8-row chunk
  const int cg8  = ((lane & 7) ^ rloc) * 8;   // swizzled source chunk (elems)
  const int q7 = q31 & 7;

  // prologue: stage tile 0 into buffer 0
#pragma unroll
  for (int i = 0; i < 2; ++i) {
    const int r0 = (wave * 2 + i) * 8;
    GLD16(kbase + (size_t)(r0 + rloc) * 64 + cg8, &Klds[0][r0 * 64]);
    GLD16(vtbase + (size_t)(r0 + rloc) * 2048 + cg8, &Vtlds[0][r0 * 64]);
  }
  __syncthreads();

  for (int kv0 = 0; kv0 < 2048; kv0 += 64) {
    const int cur = (kv0 >> 6) & 1, nxt = cur ^ 1;
    if (kv0 < 2048 - 64) {   // issue next tile early (latency hides under compute)
#pragma unroll
      for (int i = 0; i < 2; ++i) {
        const int r0 = (wave * 2 + i) * 8;
        GLD16(kbase + (size_t)(kv0 + 64 + r0 + rloc) * 64 + cg8, &Klds[nxt][r0 * 64]);
        GLD16(vtbase + (size_t)(r0 + rloc) * 2048 + (kv0 + 64) + cg8, &Vtlds[nxt][r0 * 64]);
      }
    }
    const bhalf_t* Kc = Klds[cur];
    const bhalf_t* Vc = Vtlds[cur];

    // S^T + exp2 + pack into PV B-fragments (register-only)
    bf16x8 pb[2][4];
#pragma unroll
    for (int mb = 0; mb < 2; ++mb) {
      bf16x8 ka[4];
#pragma unroll
      for (int ks = 0; ks < 4; ++ks)
        ka[ks] = *(const bf16x8*)(Kc + (mb * 32 + q31) * 64 + ((2 * ks + h) ^ q7) * 8);
#pragma unroll
      for (int qs = 0; qs < 2; ++qs) {
        f32x16 S;
#pragma unroll
        for (int i = 0; i < 16; ++i) S[i] = 0.f;
#pragma unroll
        for (int ks = 0; ks < 4; ++ks)
          S = __builtin_amdgcn_mfma_f32_32x32x16_bf16(ka[ks], qf[qs][ks], S, 0, 0, 0);
        float ls = 0.f;
#pragma unroll
        for (int half = 0; half < 2; ++half) {
          bf16x8 pk;
#pragma unroll
          for (int j = 0; j < 8; ++j) {
            const float e = __builtin_amdgcn_exp2f(S[half * 8 + j]);
            ls += e;
            pk[j] = (bhalf_t)e;
          }
          pb[qs][mb * 2 + half] = pk;
        }
        Lp[qs] += ls;
      }
    }

    // O^T += Vt @ P
#pragma unroll
    for (int dd = 0; dd < 2; ++dd)
#pragma unroll
      for (int kb = 0; kb < 4; ++kb) {
        const bf16x8 va = *(const bf16x8*)(Vc + (dd * 32 + q31) * 64 + ((2 * kb + h) ^ q7) * 8);
#pragma unroll
        for (int qs = 0; qs < 2; ++qs)
          Ot[qs][dd] = __builtin_amdgcn_mfma_f32_32x32x16_bf16(va, pb[qs][kb], Ot[qs][dd], 0, 0, 0);
      }
    __syncthreads();   // drains vmcnt (next tile landed) + read-release of buf
  }

  const int b = bh >> 4, hh = bh & 15;
#pragma unroll
  for (int qs = 0; qs < 2; ++qs) {
    const float Lt = Lp[qs] + __shfl_xor(Lp[qs], 32, 64);
    const float linv = 1.0f / Lt;
    const int s = qt * 256 + wave * 64 + qs * 32 + q31;
    bhalf_t* ob = outp + ((size_t)(b * 2048 + s)) * 1024 + hh * 64;
#pragma unroll
    for (int dd = 0; dd < 2; ++dd)
#pragma unroll
      for (int g = 0; g < 4; ++g) {
        bf16x4 o;
        o.x = (bhalf_t)(Ot[qs][dd][4 * g + 0] * linv);
        o.y = (bhalf_t)(Ot[qs][dd][4 * g + 1] * linv);
        o.z = (bhalf_t)(Ot[qs][dd][4 * g + 2] * linv);
        o.w = (bhalf_t)(Ot[qs][dd][4 * g + 3] * linv);
        *(bf16x4*)(ob + dd * 32 + g * 8 + h * 4) = o;
      }
  }
}

// ---------------------------------------------------------------------------
extern "C" void kernel_launch(void* const* d_in, const int* in_sizes, int n_in,
                              void* d_out, int out_size, void* d_ws, size_t ws_size,
                              hipStream_t stream)
{
  const float* Q  = (const float*)d_in[0];
  const float* K  = (const float*)d_in[1];
  const float* V  = (const float*)d_in[2];
  const float* Wq = (const float*)d_in[3];
  const float* bq = (const float*)d_in[4];
  const float* Wk = (const float*)d_in[5];
  const float* bk = (const float*)d_in[6];
  const float* Wv = (const float*)d_in[7];
  const float* bv = (const float*)d_in[8];
  const float* Wo = (const float*)d_in[9];
  const float* bo = (const float*)d_in[10];

  char* ws = (char*)d_ws;
  const size_t SZ = 8192ull * 1024 * 2;   // 16 MB  [8192,1024] bf16
  const size_t WZ = 1024ull * 1024 * 2;   //  2 MB  [1024,1024] bf16
  bhalf_t* Qb   = (bhalf_t*)(ws);
  bhalf_t* Kb   = (bhalf_t*)(ws + SZ);
  bhalf_t* Vb   = (bhalf_t*)(ws + 2 * SZ);
  bhalf_t* Wqb  = (bhalf_t*)(ws + 3 * SZ);
  bhalf_t* Wkb  = (bhalf_t*)(ws + 3 * SZ + WZ);
  bhalf_t* Wvb  = (bhalf_t*)(ws + 3 * SZ + 2 * WZ);
  bhalf_t* Wob  = (bhalf_t*)(ws + 3 * SZ + 3 * WZ);
  bhalf_t* q_p  = (bhalf_t*)(ws + 3 * SZ + 4 * WZ);
  bhalf_t* k_p  = (bhalf_t*)(ws + 4 * SZ + 4 * WZ);
  bhalf_t* vt_p = (bhalf_t*)(ws + 5 * SZ + 4 * WZ);
  bhalf_t* attn_o = Qb;   // alias: Qb is dead after proj_gemm

  cvt_all<<<28672, 256, 0, stream>>>(Q, K, V, Wq, Wk, Wv, Wo,
                                     Qb, Kb, Vb, Wqb, Wkb, Wvb, Wob);
  proj_gemm<<<1536, 256, 0, stream>>>(Qb, Kb, Vb, Wqb, Wkb, Wvb,
                                      bq, bk, bv, q_p, k_p, vt_p);
  attn_kernel<<<dim3(64, 8), 256, 0, stream>>>(q_p, k_p, vt_p, attn_o);
  out_gemm<<<512, 256, 0, stream>>>(attn_o, Wob, bo, (float*)d_out);
}